// Round 4
// baseline (32249.945 us; speedup 1.0000x reference)
//
#include <hip/hip_runtime.h>

#define NWG 64
#define NTHR 512
#define SEQ 2048

typedef __attribute__((ext_vector_type(8))) short short8;
typedef __attribute__((ext_vector_type(4))) float f32x4;

__device__ inline short f2bf(float f) {
  union { float f; unsigned u; } v; v.f = f;
  unsigned r = v.u + 0x7FFFu + ((v.u >> 16) & 1u);
  return (short)(r >> 16);
}

__device__ inline float sigm(float x) { return 1.f / (1.f + __expf(-x)); }
__device__ inline float tanh_(float x) { float e = __expf(2.f * x); return 1.f - 2.f / (e + 1.f); }

// coherent 16B ring read: two agent-scope relaxed u64 loads (LLC-direct; no
// fence needed anywhere). MUST be hoisted into a burst before the MFMA chain —
// interleaving with MFMA serializes 1 LLC RTT per load (round-1 lesson).
__device__ inline short8 ringld(const short* p) {
  const unsigned long long* q = (const unsigned long long*)p;
  unsigned long long lo = __hip_atomic_load(q,     __ATOMIC_RELAXED, __HIP_MEMORY_SCOPE_AGENT);
  unsigned long long hi = __hip_atomic_load(q + 1, __ATOMIC_RELAXED, __HIP_MEMORY_SCOPE_AGENT);
  union { unsigned long long u[2]; short8 s; } v;
  v.u[0] = lo; v.u[1] = hi;
  return v.s;
}

__global__ void __launch_bounds__(NTHR) lstm_kern(
    const float* __restrict__ X,
    const float* __restrict__ Wih,
    const float* __restrict__ Whh,
    const float* __restrict__ bih,
    const float* __restrict__ bhh,
    float* __restrict__ out,
    unsigned* __restrict__ flags,
    short* __restrict__ h1r,
    short* __restrict__ h2r) {
  // Per-WG: 16 hidden units -> 64 gate cols {g*512 + u0 + j, j<16}, K=1024 ([x;h])
  __shared__ short Wlds[64][1032];   // W^T bf16: [col_loc][k], k<512 ih, >=512 hh
  __shared__ float bsum[64];
  __shared__ float glds[64][36];     // gate pre-acts, col-major

  const int tid = threadIdx.x;
  const int wg = blockIdx.x;
  const int layer = wg >> 5;           // 32 WGs per layer
  const int u0 = (wg & 31) * 16;       // first hidden unit of this WG

  // ---- one-time: stage weights (bf16) + fused bias into LDS ----
  {
    const int col_loc = tid >> 3;      // 0..63
    const int l8 = tid & 7;
    const int cg = (col_loc >> 4) * 512 + u0 + (col_loc & 15);
    const float* wi = Wih + ((size_t)layer * 2048 + cg) * 512;
    const float* wh = Whh + ((size_t)layer * 2048 + cg) * 512;
    for (int k0 = l8 * 4; k0 < 512; k0 += 32) {
      float4 a = *(const float4*)(wi + k0);
      Wlds[col_loc][k0 + 0] = f2bf(a.x); Wlds[col_loc][k0 + 1] = f2bf(a.y);
      Wlds[col_loc][k0 + 2] = f2bf(a.z); Wlds[col_loc][k0 + 3] = f2bf(a.w);
      float4 b = *(const float4*)(wh + k0);
      Wlds[col_loc][512 + k0 + 0] = f2bf(b.x); Wlds[col_loc][512 + k0 + 1] = f2bf(b.y);
      Wlds[col_loc][512 + k0 + 2] = f2bf(b.z); Wlds[col_loc][512 + k0 + 3] = f2bf(b.w);
    }
    if (tid < 64) {
      const int cg2 = (tid >> 4) * 512 + u0 + (tid & 15);
      bsum[tid] = bih[layer * 2048 + cg2] + bhh[layer * 2048 + cg2];
    }
  }
  __syncthreads();

  // MFMA mapping (16x16x32 bf16): A[m=lane&15][k=quad*8+j]; D: col(lane&15)=gate, row(quad*4+reg)=batch
  const int lane = tid & 63;
  const int wid = tid >> 6;            // 0..7
  const int col = lane & 15;
  const int quad = lane >> 4;
  const int mi = wid & 1;              // batch tile (16 rows)
  const int ni = wid >> 1;             // gate-col tile (16 cols)
  const int m = mi * 16 + col;         // batch row for A
  const int nc = ni * 16 + col;        // local gate col for B/D
  const int kj = quad * 8;

  // elementwise: one cell per thread: unit eu (0..15), batch eb (0..31)
  const int eu = tid & 15;
  const int eb = tid >> 4;
  float cst = 0.f;

  short* wring = layer ? h2r : h1r;
  unsigned* wringu = (unsigned*)wring;
  const short* hring = layer ? h2r : h1r;   // own-layer h for hh part

  // accp = input-projection partial for THIS iteration's step (software pipeline)
  f32x4 accp = {0.f, 0.f, 0.f, 0.f};
  if (layer == 0) {
    const float* xrow = X + (size_t)m * SEQ * 512 + kj;   // t = 0
    #pragma unroll
    for (int s = 0; s < 16; ++s) {
      const float* xp = xrow + s * 32;
      float4 f0 = *(const float4*)xp;
      float4 f1 = *(const float4*)(xp + 4);
      short8 a;
      a[0] = f2bf(f0.x); a[1] = f2bf(f0.y); a[2] = f2bf(f0.z); a[3] = f2bf(f0.w);
      a[4] = f2bf(f1.x); a[5] = f2bf(f1.y); a[6] = f2bf(f1.z); a[7] = f2bf(f1.w);
      short8 b = *(const short8*)&Wlds[nc][s * 32 + kj];
      accp = __builtin_amdgcn_mfma_f32_16x16x32_bf16(a, b, accp, 0, 0, 0);
    }
  }

  // layer 0 computes t=p; layer 1 lags 2: t=p-2 (ring distance 2 < depth 4)
  for (int p = 0; p <= SEQ + 1; ++p) {
    const int tt = layer ? (p - 2) : p;
    const bool active = (tt >= 0) && (tt < SEQ);

    if (active) {
      f32x4 acc = accp;
      if (tt > 0) {   // hh part: the only inter-barrier-dependent compute
        // burst of 32 agent-scope u64 loads into regs (one LLC latency
        // exposure), then a pure LDS+MFMA chain. No fence needed: these
        // loads read the coherence point directly.
        const short* hrow = hring + ((size_t)((tt - 1) & 3) * 32 + m) * 512 + kj;
        short8 a[16];
        #pragma unroll
        for (int s = 0; s < 16; ++s) a[s] = ringld(hrow + s * 32);
        #pragma unroll
        for (int s = 0; s < 16; ++s) {
          short8 b = *(const short8*)&Wlds[nc][512 + s * 32 + kj];
          acc = __builtin_amdgcn_mfma_f32_16x16x32_bf16(a[s], b, acc, 0, 0, 0);
        }
      }
      const float bsv = bsum[nc];
      float4 gv;
      gv.x = acc[0] + bsv; gv.y = acc[1] + bsv; gv.z = acc[2] + bsv; gv.w = acc[3] + bsv;
      *(float4*)&glds[nc][mi * 16 + quad * 4] = gv;
    }
    __syncthreads();
    if (active) {
      const float gi = glds[eu][eb];
      const float gf = glds[16 + eu][eb];
      const float gg = glds[32 + eu][eb];
      const float go = glds[48 + eu][eb];
      cst = sigm(gf) * cst + sigm(gi) * tanh_(gg);
      const float h = sigm(go) * tanh_(cst);
      // pack bf16 pair (eu, eu^1) via shfl; even-eu lane stores u32 write-through
      const int hu = (int)(unsigned short)f2bf(h);
      const int other = __shfl_xor(hu, 1);
      if ((eu & 1) == 0) {
        const unsigned pk = (unsigned)hu | ((unsigned)other << 16);
        __hip_atomic_store(&wringu[((size_t)(tt & 3) * 32 + eb) * 256 + (u0 >> 1) + (eu >> 1)],
                           pk, __ATOMIC_RELAXED, __HIP_MEMORY_SCOPE_AGENT);
      }
      if (layer) {
        out[((size_t)eb * SEQ + tt) * 512 + u0 + eu] = h;
      }
    }
    __syncthreads();   // drains vmcnt: ring stores are LLC-visible past here
    if (tid == 0) {
      __hip_atomic_store(&flags[wg], (unsigned)(p + 1),
                         __ATOMIC_RELAXED, __HIP_MEMORY_SCOPE_AGENT);
    }

    // ---- input-projection for NEXT iteration, in the barrier-wait shadow ----
    // layer 0: X@Wih for t=p+1 (plain cached loads: X is never written).
    // layer 1: h1@Wih for t=p-1 via atomic burst. h1[p-1] availability was
    //          confirmed by the LAST poll (flags >= p); slot (p-1)&3 isn't
    //          overwritten until L0's iter p+3, which needs our flag >= p+3 —
    //          stored 2 full barrier rounds after these loads retire.
    f32x4 anew = {0.f, 0.f, 0.f, 0.f};
    if (layer == 0) {
      const int nt = p + 1;
      if (nt < SEQ) {
        const float* xrow = X + ((size_t)m * SEQ + nt) * 512 + kj;
        #pragma unroll
        for (int s = 0; s < 16; ++s) {
          const float* xp = xrow + s * 32;
          float4 f0 = *(const float4*)xp;
          float4 f1 = *(const float4*)(xp + 4);
          short8 a;
          a[0] = f2bf(f0.x); a[1] = f2bf(f0.y); a[2] = f2bf(f0.z); a[3] = f2bf(f0.w);
          a[4] = f2bf(f1.x); a[5] = f2bf(f1.y); a[6] = f2bf(f1.z); a[7] = f2bf(f1.w);
          short8 b = *(const short8*)&Wlds[nc][s * 32 + kj];
          anew = __builtin_amdgcn_mfma_f32_16x16x32_bf16(a, b, anew, 0, 0, 0);
        }
      }
    } else {
      const int nt = p - 1;
      if (nt >= 0 && nt < SEQ) {
        const short* xr = h1r + ((size_t)(nt & 3) * 32 + m) * 512 + kj;
        short8 a[16];
        #pragma unroll
        for (int s = 0; s < 16; ++s) a[s] = ringld(xr + s * 32);
        #pragma unroll
        for (int s = 0; s < 16; ++s) {
          short8 b = *(const short8*)&Wlds[nc][s * 32 + kj];
          anew = __builtin_amdgcn_mfma_f32_16x16x32_bf16(a[s], b, anew, 0, 0, 0);
        }
      }
    }
    accp = anew;

    // ---- flat distributed-flag grid barrier (64 flags = 4 cachelines) ----
    if (p <= SEQ) {
      const unsigned tgt = (unsigned)(p + 1);
      int done;
      do {
        int ok = 1;
        if (tid < NWG) {
          const unsigned f = __hip_atomic_load(&flags[tid], __ATOMIC_RELAXED,
                                               __HIP_MEMORY_SCOPE_AGENT);
          ok = (int)(f >= tgt);
        }
        done = __syncthreads_and(ok);
      } while (!done);
      __builtin_amdgcn_sched_barrier(0);  // no fence: ring reads are LLC-direct
    }
  }
}

extern "C" void kernel_launch(void* const* d_in, const int* in_sizes, int n_in,
                              void* d_out, int out_size, void* d_ws, size_t ws_size,
                              hipStream_t stream) {
  const float* X   = (const float*)d_in[0];
  const float* Wih = (const float*)d_in[1];
  const float* Whh = (const float*)d_in[2];
  const float* bih = (const float*)d_in[3];
  const float* bhh = (const float*)d_in[4];
  float* out = (float*)d_out;
  char* ws = (char*)d_ws;

  unsigned* flags = (unsigned*)ws;                       // 64 dwords (1 KB reserved)
  short* h1r = (short*)(ws + 1024);                      // [4][32][512] bf16 ring
  short* h2r = (short*)(ws + 1024 + 4 * 32 * 512 * 2);   // [4][32][512] bf16 ring

  hipMemsetAsync(ws, 0, 1024, stream);  // zero flags every launch

  void* args[] = {(void*)&X, (void*)&Wih, (void*)&Whh, (void*)&bih, (void*)&bhh,
                  (void*)&out, (void*)&flags, (void*)&h1r, (void*)&h2r};
  hipLaunchCooperativeKernel((void*)lstm_kern, dim3(NWG), dim3(NTHR), args, 0, stream);
}

// Round 5
// 25081.621 us; speedup vs baseline: 1.2858x; 1.2858x over previous
//
#include <hip/hip_runtime.h>

#define NWG 64
#define NTHR 512
#define SEQ 2048

typedef __attribute__((ext_vector_type(8))) short short8;
typedef __attribute__((ext_vector_type(4))) float f32x4;
typedef __attribute__((ext_vector_type(4))) unsigned int u32x4;

__device__ inline short f2bf(float f) {
  union { float f; unsigned u; } v; v.f = f;
  unsigned r = v.u + 0x7FFFu + ((v.u >> 16) & 1u);
  return (short)(r >> 16);
}

__device__ inline float sigm(float x) { return 1.f / (1.f + __expf(-x)); }
__device__ inline float tanh_(float x) { float e = __expf(2.f * x); return 1.f - 2.f / (e + 1.f); }

// device-coherent 16B load: bypasses L1/L2 (sc0 sc1), reads the LLC coherence
// point directly -> no acquire fence needed anywhere, caches stay warm.
// Caller must s_waitcnt vmcnt(0) + sched_barrier(0) after the burst (rule #18).
__device__ inline short8 cohld(const short* p) {
  u32x4 r;
  asm volatile("global_load_dwordx4 %0, %1, off sc0 sc1"
               : "=v"(r) : "v"(p) : "memory");
  union { u32x4 u; short8 s; } v; v.u = r;
  return v.s;
}

__global__ void __launch_bounds__(NTHR) lstm_kern(
    const float* __restrict__ X,
    const float* __restrict__ Wih,
    const float* __restrict__ Whh,
    const float* __restrict__ bih,
    const float* __restrict__ bhh,
    float* __restrict__ out,
    unsigned* __restrict__ flags,
    short* __restrict__ h1r,
    short* __restrict__ h2r) {
  // Per-WG: 16 hidden units -> 64 gate cols {g*512 + u0 + j, j<16}, K=1024 ([x;h])
  __shared__ short Wlds[64][1032];   // W^T bf16: [col_loc][k], k<512 ih, >=512 hh
  __shared__ float bsum[64];
  __shared__ float glds[64][36];     // gate pre-acts, col-major

  const int tid = threadIdx.x;
  const int wg = blockIdx.x;
  const int layer = wg >> 5;           // 32 WGs per layer
  const int u0 = (wg & 31) * 16;       // first hidden unit of this WG

  // ---- one-time: stage weights (bf16) + fused bias into LDS ----
  {
    const int col_loc = tid >> 3;      // 0..63
    const int l8 = tid & 7;
    const int cg = (col_loc >> 4) * 512 + u0 + (col_loc & 15);
    const float* wi = Wih + ((size_t)layer * 2048 + cg) * 512;
    const float* wh = Whh + ((size_t)layer * 2048 + cg) * 512;
    for (int k0 = l8 * 4; k0 < 512; k0 += 32) {
      float4 a = *(const float4*)(wi + k0);
      Wlds[col_loc][k0 + 0] = f2bf(a.x); Wlds[col_loc][k0 + 1] = f2bf(a.y);
      Wlds[col_loc][k0 + 2] = f2bf(a.z); Wlds[col_loc][k0 + 3] = f2bf(a.w);
      float4 b = *(const float4*)(wh + k0);
      Wlds[col_loc][512 + k0 + 0] = f2bf(b.x); Wlds[col_loc][512 + k0 + 1] = f2bf(b.y);
      Wlds[col_loc][512 + k0 + 2] = f2bf(b.z); Wlds[col_loc][512 + k0 + 3] = f2bf(b.w);
    }
    if (tid < 64) {
      const int cg2 = (tid >> 4) * 512 + u0 + (tid & 15);
      bsum[tid] = bih[layer * 2048 + cg2] + bhh[layer * 2048 + cg2];
    }
  }
  __syncthreads();

  // MFMA mapping (16x16x32 bf16): A[m=lane&15][k=quad*8+j]; D: col(lane&15)=gate, row(quad*4+reg)=batch
  const int lane = tid & 63;
  const int wid = tid >> 6;            // 0..7
  const int col = lane & 15;
  const int quad = lane >> 4;
  const int mi = wid & 1;              // batch tile (16 rows)
  const int ni = wid >> 1;             // gate-col tile (16 cols)
  const int m = mi * 16 + col;         // batch row for A
  const int nc = ni * 16 + col;        // local gate col for B/D
  const int kj = quad * 8;

  // elementwise: one cell per thread: unit eu (0..15), batch eb (0..31)
  const int eu = tid & 15;
  const int eb = tid >> 4;
  float cst = 0.f;

  short* wring = layer ? h2r : h1r;
  unsigned* wringu = (unsigned*)wring;
  const short* hring = layer ? h2r : h1r;   // own-layer h for hh part

  // accp = input-projection partial for THIS iteration's step (software pipeline)
  f32x4 accp = {0.f, 0.f, 0.f, 0.f};
  if (layer == 0) {
    const float* xrow = X + (size_t)m * SEQ * 512 + kj;   // t = 0
    #pragma unroll
    for (int s = 0; s < 16; ++s) {
      const float* xp = xrow + s * 32;
      float4 f0 = *(const float4*)xp;
      float4 f1 = *(const float4*)(xp + 4);
      short8 a;
      a[0] = f2bf(f0.x); a[1] = f2bf(f0.y); a[2] = f2bf(f0.z); a[3] = f2bf(f0.w);
      a[4] = f2bf(f1.x); a[5] = f2bf(f1.y); a[6] = f2bf(f1.z); a[7] = f2bf(f1.w);
      short8 b = *(const short8*)&Wlds[nc][s * 32 + kj];
      accp = __builtin_amdgcn_mfma_f32_16x16x32_bf16(a, b, accp, 0, 0, 0);
    }
  }

  // layer 0 computes t=p; layer 1 lags 2: t=p-2 (ring distance 2 < depth 4)
  for (int p = 0; p <= SEQ + 1; ++p) {
    const int tt = layer ? (p - 2) : p;
    const bool active = (tt >= 0) && (tt < SEQ);

    if (active) {
      f32x4 acc = accp;
      if (tt > 0) {   // hh part: the only inter-barrier-dependent compute
        // explicit burst of 16 coherent b128 loads -> one LLC latency
        // exposure -> waitcnt -> pure LDS+MFMA (two interleaved chains).
        const short* hrow = hring + ((size_t)((tt - 1) & 3) * 32 + m) * 512 + kj;
        short8 a[16];
        #pragma unroll
        for (int s = 0; s < 16; ++s) a[s] = cohld(hrow + s * 32);
        asm volatile("s_waitcnt vmcnt(0)" ::: "memory");
        __builtin_amdgcn_sched_barrier(0);
        f32x4 acc1 = {0.f, 0.f, 0.f, 0.f};
        #pragma unroll
        for (int s = 0; s < 16; s += 2) {
          short8 b0 = *(const short8*)&Wlds[nc][512 + s * 32 + kj];
          short8 b1 = *(const short8*)&Wlds[nc][512 + (s + 1) * 32 + kj];
          acc  = __builtin_amdgcn_mfma_f32_16x16x32_bf16(a[s], b0, acc, 0, 0, 0);
          acc1 = __builtin_amdgcn_mfma_f32_16x16x32_bf16(a[s + 1], b1, acc1, 0, 0, 0);
        }
        acc[0] += acc1[0]; acc[1] += acc1[1]; acc[2] += acc1[2]; acc[3] += acc1[3];
      }
      const float bsv = bsum[nc];
      float4 gv;
      gv.x = acc[0] + bsv; gv.y = acc[1] + bsv; gv.z = acc[2] + bsv; gv.w = acc[3] + bsv;
      *(float4*)&glds[nc][mi * 16 + quad * 4] = gv;
    }
    __syncthreads();
    if (active) {
      const float gi = glds[eu][eb];
      const float gf = glds[16 + eu][eb];
      const float gg = glds[32 + eu][eb];
      const float go = glds[48 + eu][eb];
      cst = sigm(gf) * cst + sigm(gi) * tanh_(gg);
      const float h = sigm(go) * tanh_(cst);
      // pack bf16 pair (eu, eu^1) via shfl; even-eu lane stores u32 write-through
      const int hu = (int)(unsigned short)f2bf(h);
      const int other = __shfl_xor(hu, 1);
      if ((eu & 1) == 0) {
        const unsigned pk = (unsigned)hu | ((unsigned)other << 16);
        __hip_atomic_store(&wringu[((size_t)(tt & 3) * 32 + eb) * 256 + (u0 >> 1) + (eu >> 1)],
                           pk, __ATOMIC_RELAXED, __HIP_MEMORY_SCOPE_AGENT);
      }
      if (layer) {
        out[((size_t)eb * SEQ + tt) * 512 + u0 + eu] = h;
      }
    }
    __syncthreads();   // per-wave vmcnt drain before barrier: ring stores visible
    if (tid == 0) {
      __hip_atomic_store(&flags[wg], (unsigned)(p + 1),
                         __ATOMIC_RELAXED, __HIP_MEMORY_SCOPE_AGENT);
    }

    // ---- input-projection for NEXT iteration, in the barrier-wait shadow ----
    // layer 0: X@Wih for t=p+1 (plain cached loads: X read-only; no fence ->
    //          L1/L2 stay warm across steps).
    // layer 1: h1@Wih for t=p-1 via coherent burst. Availability confirmed by
    //          the LAST poll (flags >= p); slot (p-1)&3 isn't overwritten until
    //          L0's iter p+3, which needs our flag >= p+3.
    f32x4 anew = {0.f, 0.f, 0.f, 0.f};
    if (layer == 0) {
      const int nt = p + 1;
      if (nt < SEQ) {
        const float* xrow = X + ((size_t)m * SEQ + nt) * 512 + kj;
        f32x4 an1 = {0.f, 0.f, 0.f, 0.f};
        #pragma unroll
        for (int s = 0; s < 16; ++s) {
          const float* xp = xrow + s * 32;
          float4 f0 = *(const float4*)xp;
          float4 f1 = *(const float4*)(xp + 4);
          short8 a;
          a[0] = f2bf(f0.x); a[1] = f2bf(f0.y); a[2] = f2bf(f0.z); a[3] = f2bf(f0.w);
          a[4] = f2bf(f1.x); a[5] = f2bf(f1.y); a[6] = f2bf(f1.z); a[7] = f2bf(f1.w);
          short8 b = *(const short8*)&Wlds[nc][s * 32 + kj];
          if (s & 1) an1  = __builtin_amdgcn_mfma_f32_16x16x32_bf16(a, b, an1, 0, 0, 0);
          else       anew = __builtin_amdgcn_mfma_f32_16x16x32_bf16(a, b, anew, 0, 0, 0);
        }
        anew[0] += an1[0]; anew[1] += an1[1]; anew[2] += an1[2]; anew[3] += an1[3];
      }
    } else {
      const int nt = p - 1;
      if (nt >= 0 && nt < SEQ) {
        const short* xr = h1r + ((size_t)(nt & 3) * 32 + m) * 512 + kj;
        short8 a[16];
        #pragma unroll
        for (int s = 0; s < 16; ++s) a[s] = cohld(xr + s * 32);
        asm volatile("s_waitcnt vmcnt(0)" ::: "memory");
        __builtin_amdgcn_sched_barrier(0);
        f32x4 an1 = {0.f, 0.f, 0.f, 0.f};
        #pragma unroll
        for (int s = 0; s < 16; s += 2) {
          short8 b0 = *(const short8*)&Wlds[nc][s * 32 + kj];
          short8 b1 = *(const short8*)&Wlds[nc][(s + 1) * 32 + kj];
          anew = __builtin_amdgcn_mfma_f32_16x16x32_bf16(a[s], b0, anew, 0, 0, 0);
          an1  = __builtin_amdgcn_mfma_f32_16x16x32_bf16(a[s + 1], b1, an1, 0, 0, 0);
        }
        anew[0] += an1[0]; anew[1] += an1[1]; anew[2] += an1[2]; anew[3] += an1[3];
      }
    }
    accp = anew;

    // ---- per-wave flat poll (no __syncthreads in the spin loop) ----
    // 64 flags <-> 64 lanes; each wave independently detects completion and
    // proceeds (glds writes are per-wave-disjoint; all waves already passed
    // the pre-flag barrier, so no cross-wave LDS hazard).
    if (p <= SEQ) {
      const unsigned tgt = (unsigned)(p + 1);
      for (;;) {
        const unsigned f = __hip_atomic_load(&flags[lane], __ATOMIC_RELAXED,
                                             __HIP_MEMORY_SCOPE_AGENT);
        if (__all((int)(f >= tgt))) break;
      }
      __builtin_amdgcn_sched_barrier(0);  // keep next-step loads after the poll
    }
  }
}

extern "C" void kernel_launch(void* const* d_in, const int* in_sizes, int n_in,
                              void* d_out, int out_size, void* d_ws, size_t ws_size,
                              hipStream_t stream) {
  const float* X   = (const float*)d_in[0];
  const float* Wih = (const float*)d_in[1];
  const float* Whh = (const float*)d_in[2];
  const float* bih = (const float*)d_in[3];
  const float* bhh = (const float*)d_in[4];
  float* out = (float*)d_out;
  char* ws = (char*)d_ws;

  unsigned* flags = (unsigned*)ws;                       // 64 dwords (1 KB reserved)
  short* h1r = (short*)(ws + 1024);                      // [4][32][512] bf16 ring
  short* h2r = (short*)(ws + 1024 + 4 * 32 * 512 * 2);   // [4][32][512] bf16 ring

  hipMemsetAsync(ws, 0, 1024, stream);  // zero flags every launch

  void* args[] = {(void*)&X, (void*)&Wih, (void*)&Whh, (void*)&bih, (void*)&bhh,
                  (void*)&out, (void*)&flags, (void*)&h1r, (void*)&h2r};
  hipLaunchCooperativeKernel((void*)lstm_kern, dim3(NWG), dim3(NTHR), args, 0, stream);
}

// Round 6
// 19931.142 us; speedup vs baseline: 1.6181x; 1.2584x over previous
//
#include <hip/hip_runtime.h>

#define NWG 64
#define NTHR 512
#define SEQ 2048

typedef __attribute__((ext_vector_type(8))) short short8;
typedef __attribute__((ext_vector_type(4))) float f32x4;
typedef __attribute__((ext_vector_type(4))) unsigned int u32x4;

__device__ inline short f2bf(float f) {
  union { float f; unsigned u; } v; v.f = f;
  unsigned r = v.u + 0x7FFFu + ((v.u >> 16) & 1u);
  return (short)(r >> 16);
}

__device__ inline float sigm(float x) { return 1.f / (1.f + __expf(-x)); }
__device__ inline float tanh_(float x) { float e = __expf(2.f * x); return 1.f - 2.f / (e + 1.f); }

// device-coherent 16B load: bypasses L1/L2 (sc0 sc1), reads the LLC coherence
// point directly -> no fence anywhere, cached data (X, weights) stays warm.
// Caller must s_waitcnt vmcnt(0) + sched_barrier(0) before using results.
__device__ inline short8 cohld(const short* p) {
  u32x4 r;
  asm volatile("global_load_dwordx4 %0, %1, off sc0 sc1"
               : "=v"(r) : "v"(p) : "memory");
  union { u32x4 u; short8 s; } v; v.u = r;
  return v.s;
}

__global__ void __launch_bounds__(NTHR) lstm_kern(
    const float* __restrict__ X,
    const float* __restrict__ Wih,
    const float* __restrict__ Whh,
    const float* __restrict__ bih,
    const float* __restrict__ bhh,
    float* __restrict__ out,
    unsigned* __restrict__ flags,
    short* __restrict__ h1r,
    short* __restrict__ h2r) {
  // Per-WG: 16 hidden units -> 64 gate cols; K=512 per matrix; weights in VGPRs.
  // LDS only holds: staged h matrix (dedup of the LLC broadcast), gate pre-acts, bias.
  __shared__ short hstg[32][520];    // staged h (32 batch x 512 units bf16), +8 pad
  __shared__ float glds[64][36];     // gate pre-acts, col-major
  __shared__ float bsum[64];

  const int tid = threadIdx.x;
  const int wg = blockIdx.x;
  const int layer = wg >> 5;           // 32 WGs per layer
  const int u0 = (wg & 31) * 16;       // first hidden unit of this WG

  // MFMA mapping (16x16x32 bf16): A[m=lane&15][k=quad*8+j]; D: col(lane&15)=gate, row(quad*4+reg)=batch
  const int lane = tid & 63;
  const int wid = tid >> 6;            // 0..7
  const int col = lane & 15;
  const int quad = lane >> 4;
  const int mi = wid & 1;              // batch tile (16 rows)
  const int ni = wid >> 1;             // gate-col tile (16 cols)
  const int m = mi * 16 + col;         // batch row for A
  const int nc = ni * 16 + col;        // local gate col for B/D
  const int kj = quad * 8;

  // staging geometry: wave stages rows 4*wid..4*wid+3; lane covers 16B stripes
  const int sr = 4 * wid + (lane >> 4);   // staged row (batch)
  const int sq = (lane & 15) * 8;         // short offset of 16B stripe

  // ---- one-time: bias to LDS, weight B-fragments to REGISTERS ----
  if (tid < 64) {
    const int cg2 = (tid >> 4) * 512 + u0 + (tid & 15);
    bsum[tid] = bih[layer * 2048 + cg2] + bhh[layer * 2048 + cg2];
  }
  short8 wih_f[16], whh_f[16];
  {
    const int cg = ni * 512 + u0 + col;   // this lane's gate row
    const float* wi = Wih + ((size_t)layer * 2048 + cg) * 512 + kj;
    const float* wh = Whh + ((size_t)layer * 2048 + cg) * 512 + kj;
    #pragma unroll
    for (int s = 0; s < 16; ++s) {
      float4 a0 = *(const float4*)(wi + s * 32);
      float4 a1 = *(const float4*)(wi + s * 32 + 4);
      short8 v;
      v[0] = f2bf(a0.x); v[1] = f2bf(a0.y); v[2] = f2bf(a0.z); v[3] = f2bf(a0.w);
      v[4] = f2bf(a1.x); v[5] = f2bf(a1.y); v[6] = f2bf(a1.z); v[7] = f2bf(a1.w);
      wih_f[s] = v;
      float4 b0 = *(const float4*)(wh + s * 32);
      float4 b1 = *(const float4*)(wh + s * 32 + 4);
      short8 u;
      u[0] = f2bf(b0.x); u[1] = f2bf(b0.y); u[2] = f2bf(b0.z); u[3] = f2bf(b0.w);
      u[4] = f2bf(b1.x); u[5] = f2bf(b1.y); u[6] = f2bf(b1.z); u[7] = f2bf(b1.w);
      whh_f[s] = u;
    }
  }
  __syncthreads();

  // elementwise: one cell per thread: unit eu (0..15), batch eb (0..31)
  const int eu = tid & 15;
  const int eb = tid >> 4;
  float cst = 0.f;

  short* wring = layer ? h2r : h1r;
  unsigned* wringu = (unsigned*)wring;
  const short* hring = layer ? h2r : h1r;   // own-layer h for hh part

  // accp = input-projection partial for THIS iteration's step (software pipeline)
  f32x4 accp = {0.f, 0.f, 0.f, 0.f};
  if (layer == 0) {
    const float* xrow = X + (size_t)m * SEQ * 512 + kj;   // t = 0
    #pragma unroll
    for (int s = 0; s < 16; ++s) {
      const float* xp = xrow + s * 32;
      float4 f0 = *(const float4*)xp;
      float4 f1 = *(const float4*)(xp + 4);
      short8 a;
      a[0] = f2bf(f0.x); a[1] = f2bf(f0.y); a[2] = f2bf(f0.z); a[3] = f2bf(f0.w);
      a[4] = f2bf(f1.x); a[5] = f2bf(f1.y); a[6] = f2bf(f1.z); a[7] = f2bf(f1.w);
      accp = __builtin_amdgcn_mfma_f32_16x16x32_bf16(a, wih_f[s], accp, 0, 0, 0);
    }
  }

  // layer 0 computes t=p; layer 1 lags 2: t=p-2 (ring distance 2 < depth 4)
  for (int p = 0; p <= SEQ + 1; ++p) {
    const int tt = layer ? (p - 2) : p;
    const bool active = (tt >= 0) && (tt < SEQ);

    if (active) {
      f32x4 acc = accp;
      if (tt > 0) {   // hh part: stage h(t-1) ONCE per WG (32 KB), MFMA from LDS
        const short* src = hring + (size_t)((tt - 1) & 3) * 32 * 512 + sr * 512 + sq;
        short8 v0 = cohld(src);
        short8 v1 = cohld(src + 128);
        short8 v2 = cohld(src + 256);
        short8 v3 = cohld(src + 384);
        asm volatile("s_waitcnt vmcnt(0)" ::: "memory");
        __builtin_amdgcn_sched_barrier(0);
        *(short8*)&hstg[sr][sq]       = v0;
        *(short8*)&hstg[sr][sq + 128] = v1;
        *(short8*)&hstg[sr][sq + 256] = v2;
        *(short8*)&hstg[sr][sq + 384] = v3;
        __syncthreads();   // hstg ready for all waves
        f32x4 acc1 = {0.f, 0.f, 0.f, 0.f};
        #pragma unroll
        for (int s = 0; s < 16; s += 2) {
          short8 a0 = *(const short8*)&hstg[m][s * 32 + kj];
          short8 a1 = *(const short8*)&hstg[m][(s + 1) * 32 + kj];
          acc  = __builtin_amdgcn_mfma_f32_16x16x32_bf16(a0, whh_f[s], acc, 0, 0, 0);
          acc1 = __builtin_amdgcn_mfma_f32_16x16x32_bf16(a1, whh_f[s + 1], acc1, 0, 0, 0);
        }
        acc[0] += acc1[0]; acc[1] += acc1[1]; acc[2] += acc1[2]; acc[3] += acc1[3];
      }
      const float bsv = bsum[nc];
      float4 gv;
      gv.x = acc[0] + bsv; gv.y = acc[1] + bsv; gv.z = acc[2] + bsv; gv.w = acc[3] + bsv;
      *(float4*)&glds[nc][mi * 16 + quad * 4] = gv;
    }
    __syncthreads();
    if (active) {
      const float gi = glds[eu][eb];
      const float gf = glds[16 + eu][eb];
      const float gg = glds[32 + eu][eb];
      const float go = glds[48 + eu][eb];
      cst = sigm(gf) * cst + sigm(gi) * tanh_(gg);
      const float h = sigm(go) * tanh_(cst);
      // pack bf16 pair (eu, eu^1) via shfl; even-eu lane stores u32 write-through
      const int hu = (int)(unsigned short)f2bf(h);
      const int other = __shfl_xor(hu, 1);
      if ((eu & 1) == 0) {
        const unsigned pk = (unsigned)hu | ((unsigned)other << 16);
        __hip_atomic_store(&wringu[((size_t)(tt & 3) * 32 + eb) * 256 + (u0 >> 1) + (eu >> 1)],
                           pk, __ATOMIC_RELAXED, __HIP_MEMORY_SCOPE_AGENT);
      }
      if (layer) {
        out[((size_t)eb * SEQ + tt) * 512 + u0 + eu] = h;
      }
    }
    __syncthreads();   // drains vmcnt: ring stores visible; also fences hstg reuse below
    if (tid == 0) {
      __hip_atomic_store(&flags[wg], (unsigned)(p + 1),
                         __ATOMIC_RELAXED, __HIP_MEMORY_SCOPE_AGENT);
    }

    // ---- input-projection for NEXT iteration, in the barrier-wait shadow ----
    // layer 0: X@Wih for t=p+1 (plain cached loads; X read-only, caches warm).
    // layer 1: h1@Wih for t=p-1 (flag-confirmed by the LAST poll; slot (p-1)&3
    //          isn't overwritten until L0's iter p+3, needing our flag >= p+3).
    f32x4 anew = {0.f, 0.f, 0.f, 0.f};
    if (layer == 0) {
      const int nt = p + 1;
      if (nt < SEQ) {
        const float* xrow = X + ((size_t)m * SEQ + nt) * 512 + kj;
        f32x4 an1 = {0.f, 0.f, 0.f, 0.f};
        #pragma unroll
        for (int s = 0; s < 16; ++s) {
          const float* xp = xrow + s * 32;
          float4 f0 = *(const float4*)xp;
          float4 f1 = *(const float4*)(xp + 4);
          short8 a;
          a[0] = f2bf(f0.x); a[1] = f2bf(f0.y); a[2] = f2bf(f0.z); a[3] = f2bf(f0.w);
          a[4] = f2bf(f1.x); a[5] = f2bf(f1.y); a[6] = f2bf(f1.z); a[7] = f2bf(f1.w);
          if (s & 1) an1  = __builtin_amdgcn_mfma_f32_16x16x32_bf16(a, wih_f[s], an1, 0, 0, 0);
          else       anew = __builtin_amdgcn_mfma_f32_16x16x32_bf16(a, wih_f[s], anew, 0, 0, 0);
        }
        anew[0] += an1[0]; anew[1] += an1[1]; anew[2] += an1[2]; anew[3] += an1[3];
      }
    } else {
      const int nt = p - 1;
      if (nt >= 0 && nt < SEQ) {
        // stage h1[nt] (32 KB dedup) -> hstg; safe: all hstg reads of the hh
        // phase completed before the post-elementwise __syncthreads above.
        const short* src = h1r + (size_t)(nt & 3) * 32 * 512 + sr * 512 + sq;
        short8 v0 = cohld(src);
        short8 v1 = cohld(src + 128);
        short8 v2 = cohld(src + 256);
        short8 v3 = cohld(src + 384);
        asm volatile("s_waitcnt vmcnt(0)" ::: "memory");
        __builtin_amdgcn_sched_barrier(0);
        *(short8*)&hstg[sr][sq]       = v0;
        *(short8*)&hstg[sr][sq + 128] = v1;
        *(short8*)&hstg[sr][sq + 256] = v2;
        *(short8*)&hstg[sr][sq + 384] = v3;
        __syncthreads();   // hstg ready (WG-uniform branch)
        f32x4 an1 = {0.f, 0.f, 0.f, 0.f};
        #pragma unroll
        for (int s = 0; s < 16; s += 2) {
          short8 a0 = *(const short8*)&hstg[m][s * 32 + kj];
          short8 a1 = *(const short8*)&hstg[m][(s + 1) * 32 + kj];
          anew = __builtin_amdgcn_mfma_f32_16x16x32_bf16(a0, wih_f[s], anew, 0, 0, 0);
          an1  = __builtin_amdgcn_mfma_f32_16x16x32_bf16(a1, wih_f[s + 1], an1, 0, 0, 0);
        }
        anew[0] += an1[0]; anew[1] += an1[1]; anew[2] += an1[2]; anew[3] += an1[3];
      }
    }
    accp = anew;

    // ---- per-wave flat poll (no __syncthreads in the spin loop) ----
    if (p <= SEQ) {
      const unsigned tgt = (unsigned)(p + 1);
      for (;;) {
        const unsigned f = __hip_atomic_load(&flags[lane], __ATOMIC_RELAXED,
                                             __HIP_MEMORY_SCOPE_AGENT);
        if (__all((int)(f >= tgt))) break;
      }
      __builtin_amdgcn_sched_barrier(0);
    }
    __syncthreads();   // all waves past poll before next-iter stage overwrites hstg
  }
}

extern "C" void kernel_launch(void* const* d_in, const int* in_sizes, int n_in,
                              void* d_out, int out_size, void* d_ws, size_t ws_size,
                              hipStream_t stream) {
  const float* X   = (const float*)d_in[0];
  const float* Wih = (const float*)d_in[1];
  const float* Whh = (const float*)d_in[2];
  const float* bih = (const float*)d_in[3];
  const float* bhh = (const float*)d_in[4];
  float* out = (float*)d_out;
  char* ws = (char*)d_ws;

  unsigned* flags = (unsigned*)ws;                       // 64 dwords (1 KB reserved)
  short* h1r = (short*)(ws + 1024);                      // [4][32][512] bf16 ring
  short* h2r = (short*)(ws + 1024 + 4 * 32 * 512 * 2);   // [4][32][512] bf16 ring

  hipMemsetAsync(ws, 0, 1024, stream);  // zero flags every launch

  void* args[] = {(void*)&X, (void*)&Wih, (void*)&Whh, (void*)&bih, (void*)&bhh,
                  (void*)&out, (void*)&flags, (void*)&h1r, (void*)&h2r};
  hipLaunchCooperativeKernel((void*)lstm_kern, dim3(NWG), dim3(NTHR), args, 0, stream);
}